// Round 7
// baseline (445.597 us; speedup 1.0000x reference)
//
#include <hip/hip_runtime.h>
#include <hip/hip_bf16.h>

typedef __hip_bfloat16 bf16;
typedef __attribute__((ext_vector_type(8))) short bf16x8;
typedef __attribute__((ext_vector_type(4))) short short4v;
typedef __attribute__((ext_vector_type(4))) float f32x4;

#define BATCH 2
#define CH 64
#define NPIX 65536  // 256*256
#define HDIM 256
#define NLAYER 4
#define NGRP 8

// ---- workspace byte offsets ----
// feat is [b][px][c] (c-minor) f32
#define OFS_FEAT   0ull
#define OFS_KX     33554432ull   // 4 reps x 2 b x 4096 f = 131072 B (KX accumulators)
#define OFS_FSUM   33685504ull   // 16384 B (strided x32)
#define OFS_KGS    33701888ull   // 16384 B (strided x32)
#define OFS_SSUM   33718272ull   // 16384 B (2 ping x strided)
#define OFS_BEFF   33734656ull   // 512 B
#define OFS_MEFFB  33735168ull   // 16384 B (bf16)
#define OFS_WKB    33751552ull   // 32768 B
#define OFS_WVB    33784320ull   // 32768 B
#define OFS_WGB    33817088ull   // 65536 B
#define OFS_WTOUT  33882624ull   // 4608 B  ([o][k][c] f32)
#define OFS_WPB    33887232ull   // 32768 B (bf16)
#define OFS_WQTB   33920000ull   // 32768 B (bf16, transposed [e][c])
#define ZERO_BYTES 180224        // KX + fsum + kgs + ssum (contiguous)

__device__ __forceinline__ float sigmoidf_(float x){ return 1.0f/(1.0f+__expf(-x)); }

// f32 -> bf16 bits, round-to-nearest-even
__device__ __forceinline__ short f2bs(float x){
  unsigned u = __float_as_uint(x);
  u += 0x7fffu + ((u >> 16) & 1u);
  return (short)(u >> 16);
}

__device__ __forceinline__ float waveReduce(float v){
  #pragma unroll
  for (int off=32; off; off>>=1) v += __shfl_xor(v, off, 64);
  return v;
}

// ---------- weight pre-convert ----------
__global__ void k_prepw(const float* __restrict__ Wk, const float* __restrict__ Wv,
                        const float* __restrict__ Wg, const float* __restrict__ Wout,
                        const float* __restrict__ Wp, const float* __restrict__ Wq,
                        short* __restrict__ Wkb, short* __restrict__ Wvb,
                        short* __restrict__ Wgb, float* __restrict__ wtout,
                        short* __restrict__ Wpb, short* __restrict__ Wqtb){
  int i = blockIdx.x*256 + threadIdx.x;
  if (i < 16384){
    Wkb[i] = f2bs(Wk[i]);
    Wvb[i] = f2bs(Wv[i]);
    Wpb[i] = f2bs(Wp[i]);
    int l = i >> 12, within = i & 4095;
    int e = within >> 6, c = within & 63;
    Wqtb[i] = f2bs(Wq[l*4096 + c*64 + e]);   // WqT[e][c] = Wq[c][e]
  }
  if (i < 32768) Wgb[i] = f2bs(Wg[i]);
  if (i < 1152){
    int o = i / 576, rem = i % 576;
    int k = rem >> 6, c = rem & 63;
    wtout[(o*9 + k)*64 + c] = Wout[o*576 + c*9 + k];
  }
}

// ---------- per-block group-stat reduction (conv_in); ssum entries strided x32 ----------
__device__ __forceinline__ void blockStats(const float* gs, const float* gq,
                                           float* ssum_b, int t){
  __shared__ float sacc[16];
  if (t < 16) sacc[t] = 0.f;
  __syncthreads();
  #pragma unroll
  for (int g=0; g<NGRP; g++){
    float s  = waveReduce(gs[g]);
    float sq = waveReduce(gq[g]);
    if ((t & 63) == 0){ atomicAdd(&sacc[g*2], s); atomicAdd(&sacc[g*2+1], sq); }
  }
  __syncthreads();
  if (t < 16) atomicAdd(&ssum_b[t*32], sacc[t]);
}

// ---------- conv3x3 2->64 + fused GN stats; feat out [px][c] ----------
__global__ void k_conv_in(const float* __restrict__ x, const float* __restrict__ w,
                          const float* __restrict__ bias,
                          float* __restrict__ feat, float* __restrict__ ssum){
  int b = blockIdx.y;
  int t = threadIdx.x;
  int n = blockIdx.x*256 + t;
  int y = n >> 8, xx = n & 255;
  float patch[18];
  int idx = 0;
  #pragma unroll
  for (int ci=0; ci<2; ci++)
    #pragma unroll
    for (int dy=-1; dy<=1; dy++)
      #pragma unroll
      for (int dx=-1; dx<=1; dx++){
        int yy = y+dy, xc = xx+dx;
        float v = 0.f;
        if (yy>=0 && yy<HDIM && xc>=0 && xc<HDIM)
          v = x[((b*2+ci)*HDIM + yy)*HDIM + xc];
        patch[idx++] = v;
      }
  float gs[NGRP], gq[NGRP];
  #pragma unroll
  for (int g=0; g<NGRP; g++){ gs[g]=0.f; gq[g]=0.f; }
  float* fb = feat + ((size_t)b*NPIX + n)*64;
  #pragma unroll
  for (int c4=0; c4<16; c4++){
    f32x4 ov;
    #pragma unroll
    for (int j=0;j<4;j++){
      int o = c4*4 + j;
      float acc = bias[o];
      #pragma unroll
      for (int k=0; k<18; k++) acc += w[o*18+k]*patch[k];
      ov[j] = acc;
      gs[o>>3] += acc; gq[o>>3] += acc*acc;
    }
    *(f32x4*)(fb + c4*4) = ov;
  }
  blockStats(gs, gq, ssum + b*512, t);
}

// ---------- GN coefficient compute (ssum strided) ----------
__device__ __forceinline__ void gnCoef(const float* __restrict__ ssum_l, int b, int t,
                                       const float* __restrict__ gammaP,
                                       const float* __restrict__ betaP, int l,
                                       float* s_gnA, float* s_gnB){
  if (t < 64){
    int g = t >> 3;
    const float inv = 1.0f/(8.0f*NPIX);
    float s  = ssum_l[(b*16 + g*2)*32];
    float sq = ssum_l[(b*16 + g*2 + 1)*32];
    float mu = s*inv;
    float var = sq*inv - mu*mu;
    float rstd = rsqrtf(var + 1e-5f);
    float A = rstd * gammaP[l*64 + t];
    s_gnA[t] = A;
    s_gnB[t] = betaP[l*64 + t] - mu * A;
  }
}

// ---------- MFMA: GN + k/i/f GEMMs + KX outer product; 128 px per block ----------
// know is computed later as KX*Wv^T + kgsum (x) bv  (v-GEMM eliminated)
__global__ __launch_bounds__(256,3) void k_qkvg_know(
    const float* __restrict__ feat, const float* __restrict__ ssum_l,
    const float* __restrict__ gammaP, const float* __restrict__ betaP,
    const short* __restrict__ Wkb, const float* __restrict__ bkP,
    const short* __restrict__ Wgb, const float* __restrict__ bgP,
    int l, float* __restrict__ kx, float* __restrict__ f_sum,
    float* __restrict__ kg_sum)
{
  int b = blockIdx.y;
  int n0 = blockIdx.x * 128;
  int rep = blockIdx.x & 3;
  int t = threadIdx.x;
  int w = t >> 6;
  int lane = t & 63;
  int m = lane & 15;
  int quad = lane >> 4;
  int rowbase = w*16;

  __shared__ short s_xn[128*72];    // [px][c]; aliased by s_kg after B-frag reads
  __shared__ short s_xnT[64*136];   // [c][px]
  __shared__ float s_gnA[64], s_gnB[64];
  short* s_kg = s_xn;               // [c][px] stride 136 (8704 shorts <= 9216)

  // ---- prefetch feat tile into regs (before any barrier) ----
  const float* fbase = feat + ((size_t)b*NPIX + n0)*64;
  f32x4 fv[8];
  #pragma unroll
  for (int i=0;i<8;i++){
    int chunk = t + i*256;
    fv[i] = *(const f32x4*)(fbase + (chunk >> 4)*64 + (chunk & 15)*4);
  }

  gnCoef(ssum_l, b, t, gammaP, betaP, l, s_gnA, s_gnB);

  float bkv[4], biv[4], bfv[4], fs[4], kgs[4];
  #pragma unroll
  for (int r=0;r<4;r++){
    int row = rowbase + quad*4 + r;
    bkv[r] = bkP[l*64 + row];
    biv[r] = bgP[l*128 + 64 + row];
    bfv[r] = bgP[l*128 + row];
    fs[r] = 0.f; kgs[r] = 0.f;
  }
  f32x4 z4 = {0.f,0.f,0.f,0.f};

  __syncthreads();  // barrier 1: gn coefs ready

  // ---- GN + convert + write both layouts ----
  #pragma unroll
  for (int i=0;i<8;i++){
    int chunk = t + i*256;
    int px = chunk >> 4, c0 = (chunk & 15)*4;
    short4v xs;
    #pragma unroll
    for (int j=0;j<4;j++)
      xs[j] = f2bs(fmaf(fv[i][j], s_gnA[c0+j], s_gnB[c0+j]));
    *(short4v*)&s_xn[px*72 + c0] = xs;
    #pragma unroll
    for (int j=0;j<4;j++)
      s_xnT[(c0+j)*136 + px] = xs[j];
  }
  __syncthreads();  // barrier 2: tiles staged

  // ---- B-fragments for k/i/f GEMMs ----
  bf16x8 Bf[2][8];
  #pragma unroll
  for (int kc=0;kc<2;kc++)
    #pragma unroll
    for (int nt=0;nt<8;nt++)
      Bf[kc][nt] = *(const bf16x8*)&s_xn[(nt*16+m)*72 + kc*32 + quad*8];
  __syncthreads();  // barrier 3: s_xn dead -> s_kg writable

  // ---- k & i GEMMs -> kg (own rows) + kgsum ----
  {
    bf16x8 Ak[2], Ai[2];
    #pragma unroll
    for (int kc=0;kc<2;kc++){
      Ak[kc] = *(const bf16x8*)&Wkb[l*4096 + (rowbase+m)*64 + kc*32 + quad*8];
      Ai[kc] = *(const bf16x8*)&Wgb[l*8192 + (64+rowbase+m)*64 + kc*32 + quad*8];
    }
    #pragma unroll
    for (int half=0; half<2; half++){
      f32x4 acck[4], acci[4];
      #pragma unroll
      for (int q4=0;q4<4;q4++){ acck[q4]=z4; acci[q4]=z4; }
      #pragma unroll
      for (int kc=0;kc<2;kc++)
        #pragma unroll
        for (int q4=0;q4<4;q4++){
          acck[q4] = __builtin_amdgcn_mfma_f32_16x16x32_bf16(Ak[kc], Bf[kc][half*4+q4], acck[q4], 0,0,0);
          acci[q4] = __builtin_amdgcn_mfma_f32_16x16x32_bf16(Ai[kc], Bf[kc][half*4+q4], acci[q4], 0,0,0);
        }
      #pragma unroll
      for (int q4=0;q4<4;q4++){
        int nt = half*4+q4;
        #pragma unroll
        for (int r=0;r<4;r++){
          int row = rowbase + quad*4 + r;
          float kv = acck[q4][r] + bkv[r];
          float iv = acci[q4][r] + biv[r];
          float kgv = kv * sigmoidf_(iv);
          s_kg[row*136 + nt*16 + m] = f2bs(kgv);
          kgs[r] += kgv;
        }
      }
    }
  }
  // ---- f GEMM -> fs (independent, overlaps) ----
  {
    bf16x8 Af[2];
    #pragma unroll
    for (int kc=0;kc<2;kc++)
      Af[kc] = *(const bf16x8*)&Wgb[l*8192 + (rowbase+m)*64 + kc*32 + quad*8];
    #pragma unroll
    for (int half=0; half<2; half++){
      f32x4 accf[4];
      #pragma unroll
      for (int q4=0;q4<4;q4++) accf[q4]=z4;
      #pragma unroll
      for (int kc=0;kc<2;kc++)
        #pragma unroll
        for (int q4=0;q4<4;q4++)
          accf[q4] = __builtin_amdgcn_mfma_f32_16x16x32_bf16(Af[kc], Bf[kc][half*4+q4], accf[q4], 0,0,0);
      #pragma unroll
      for (int q4=0;q4<4;q4++)
        #pragma unroll
        for (int r=0;r<4;r++)
          fs[r] += sigmoidf_(accf[q4][r] + bfv[r]);
    }
  }

  // ---- KX: own-wave kg rows (ds ordering, no barrier) x xnT ----
  f32x4 accn[4];
  #pragma unroll
  for (int dt=0;dt<4;dt++) accn[dt] = z4;
  #pragma unroll
  for (int kc4=0; kc4<4; kc4++){
    bf16x8 a = *(const bf16x8*)&s_kg[(rowbase + m)*136 + kc4*32 + quad*8];
    #pragma unroll
    for (int dt=0; dt<4; dt++){
      bf16x8 bx = *(const bf16x8*)&s_xnT[(dt*16 + m)*136 + kc4*32 + quad*8];
      accn[dt] = __builtin_amdgcn_mfma_f32_16x16x32_bf16(a, bx, accn[dt], 0,0,0);
    }
  }

  // ---- reductions: fs & kgs over 16 m-lanes ----
  #pragma unroll
  for (int off=1; off<16; off<<=1)
    #pragma unroll
    for (int r=0;r<4;r++){
      fs[r]  += __shfl_xor(fs[r],  off, 64);
      kgs[r] += __shfl_xor(kgs[r], off, 64);
    }
  if (m == 0){
    #pragma unroll
    for (int r=0;r<4;r++){
      int row = rowbase + quad*4 + r;
      atomicAdd(&f_sum[(b*64 + row)*32], fs[r]);
      atomicAdd(&kg_sum[(b*64 + row)*32], kgs[r]);
    }
  }
  // ---- KX atomics -> replica ----
  float* kr = kx + (size_t)(rep*2 + b)*4096;
  #pragma unroll
  for (int dt=0;dt<4;dt++)
    #pragma unroll
    for (int r=0;r<4;r++)
      atomicAdd(&kr[(rowbase + quad*4 + r)*64 + dt*16 + m], accn[dt][r]);
}

// ---------- mem = fmean*prev + (KX*Wv^T + kgsum(x)bv)/N; Meff, beff via MFMA ----------
__global__ __launch_bounds__(256) void k_memupd_meff(
    float* __restrict__ kx, float* __restrict__ f_sum, float* __restrict__ kg_sum,
    const float* __restrict__ hidden_in,
    const short* __restrict__ Wvb, const float* __restrict__ bvP,
    const short* __restrict__ Wpb, const short* __restrict__ Wqtb,
    const float* __restrict__ bqP, const float* __restrict__ bpP,
    int l, float* __restrict__ hidden_out,
    short* __restrict__ Meffb, float* __restrict__ beff,
    float* __restrict__ ssum_next)
{
  int b = blockIdx.x;
  int t = threadIdx.x;
  int w = t >> 6;
  int lane = t & 63;
  int m = lane & 15;
  int quad = lane >> 4;
  const float invN = 1.0f/(float)NPIX;

  __shared__ short s_kxb[64*72];   // KX[c][e] bf16
  __shared__ short s_memb[64*72];  // mem[c][d] bf16
  __shared__ short s_mfb[64*72];   // mf[o][c] bf16
  __shared__ float s_bq[64], s_bv[64], s_fm[64], s_kgs[64];

  if (t < 64){
    s_bq[t]  = bqP[l*64 + t];
    s_bv[t]  = bvP[l*64 + t];
    s_fm[t]  = f_sum[(b*64 + t)*32] * invN;
    s_kgs[t] = kg_sum[(b*64 + t)*32] * invN;
  }
  #pragma unroll
  for (int i=0;i<16;i++){
    int ce = t + i*256;
    float s = 0.f;
    #pragma unroll
    for (int rep=0; rep<4; rep++){
      s += kx[(size_t)(rep*2+b)*4096 + ce];
      kx[(size_t)(rep*2+b)*4096 + ce] = 0.f;
    }
    s_kxb[(ce>>6)*72 + (ce&63)] = f2bs(s);
  }
  __syncthreads();
  if (t < 64){ f_sum[(b*64+t)*32] = 0.f; kg_sum[(b*64+t)*32] = 0.f; }
  if (t < 16) ssum_next[(b*16+t)*32] = 0.f;

  f32x4 z4 = {0.f,0.f,0.f,0.f};

  // ---- GEMM0: tmp[c][d] = sum_e KX[c,e]*Wv[d,e]; epilogue builds mem ----
  bf16x8 Akx[2];
  #pragma unroll
  for (int kc=0;kc<2;kc++)
    Akx[kc] = *(const bf16x8*)&s_kxb[(w*16+m)*72 + kc*32 + quad*8];
  float pm[4][4];
  #pragma unroll
  for (int ct=0; ct<4; ct++)
    #pragma unroll
    for (int r=0;r<4;r++)
      pm[ct][r] = hidden_in[(size_t)(b*NLAYER+l)*4096 + (w*16+quad*4+r)*64 + ct*16+m];
  #pragma unroll
  for (int ct=0; ct<4; ct++){
    f32x4 a = z4;
    #pragma unroll
    for (int kc=0;kc<2;kc++){
      bf16x8 Bv = *(const bf16x8*)&Wvb[l*4096 + (ct*16+m)*64 + kc*32 + quad*8];
      a = __builtin_amdgcn_mfma_f32_16x16x32_bf16(Akx[kc], Bv, a, 0,0,0);
    }
    #pragma unroll
    for (int r=0;r<4;r++){
      int c = w*16 + quad*4 + r;
      int d = ct*16 + m;
      float nm = s_fm[c]*pm[ct][r] + a[r]*invN + s_kgs[c]*s_bv[d];
      hidden_out[(size_t)(b*NLAYER+l)*4096 + c*64 + d] = nm;
      s_memb[c*72 + d] = f2bs(nm);
    }
  }
  __syncthreads();

  // ---- GEMM1: mf[o][c] = sum_d Wp[o,d]*mem[c,d]; beff folded ----
  bf16x8 Ap[2];
  #pragma unroll
  for (int kc=0;kc<2;kc++)
    Ap[kc] = *(const bf16x8*)&Wpb[l*4096 + (w*16+m)*64 + kc*32 + quad*8];
  float be[4];
  #pragma unroll
  for (int r=0;r<4;r++) be[r] = 0.f;
  #pragma unroll
  for (int ct=0; ct<4; ct++){
    f32x4 a = z4;
    #pragma unroll
    for (int kc=0;kc<2;kc++){
      bf16x8 Bm = *(const bf16x8*)&s_memb[(ct*16+m)*72 + kc*32 + quad*8];
      a = __builtin_amdgcn_mfma_f32_16x16x32_bf16(Ap[kc], Bm, a, 0,0,0);
    }
    int c = ct*16 + m;
    #pragma unroll
    for (int r=0;r<4;r++){
      int o = w*16 + quad*4 + r;
      s_mfb[o*72 + c] = f2bs(a[r]);
      be[r] += a[r] * s_bq[c];
    }
  }
  #pragma unroll
  for (int off=1; off<16; off<<=1)
    #pragma unroll
    for (int r=0;r<4;r++) be[r] += __shfl_xor(be[r], off, 64);
  if (m == 0){
    #pragma unroll
    for (int r=0;r<4;r++){
      int o = w*16 + quad*4 + r;
      beff[b*64 + o] = bpP[l*64 + o] + 0.125f*be[r];
    }
  }
  __syncthreads();

  // ---- GEMM2: Meff[o][e] = 0.125 * sum_c mf[o,c]*WqT[e,c] ----
  bf16x8 Am2[2];
  #pragma unroll
  for (int kc=0;kc<2;kc++)
    Am2[kc] = *(const bf16x8*)&s_mfb[(w*16+m)*72 + kc*32 + quad*8];
  #pragma unroll
  for (int et=0; et<4; et++){
    f32x4 a = z4;
    #pragma unroll
    for (int kc=0;kc<2;kc++){
      bf16x8 Bq = *(const bf16x8*)&Wqtb[l*4096 + (et*16+m)*64 + kc*32 + quad*8];
      a = __builtin_amdgcn_mfma_f32_16x16x32_bf16(Am2[kc], Bq, a, 0,0,0);
    }
    #pragma unroll
    for (int r=0;r<4;r++){
      int o = w*16 + quad*4 + r;
      Meffb[(size_t)b*4096 + o*64 + et*16 + m] = f2bs(0.125f*a[r]);
    }
  }
}

// ---------- retrieval+proj+residual: direct f32x4 RMW epilogue + GN stats ----------
__global__ __launch_bounds__(256,3) void k_retrproj(
    const float* __restrict__ ssum_l,
    const float* __restrict__ gammaP, const float* __restrict__ betaP,
    const short* __restrict__ Meffb, const float* __restrict__ beff,
    int l, float* __restrict__ feat, float* __restrict__ ssum_next)
{
  int b = blockIdx.y;
  int n0 = blockIdx.x * 128;
  int t = threadIdx.x;
  int w = t >> 6;
  int lane = t & 63;
  int m = lane & 15;
  int quad = lane >> 4;

  __shared__ short s_xn[128*72];
  __shared__ float s_gnA[64], s_gnB[64], s_beff[64];
  __shared__ float s_sacc[16];

  // prefetch feat tile
  const float* fbase = feat + ((size_t)b*NPIX + n0)*64;
  f32x4 fv[8];
  #pragma unroll
  for (int i=0;i<8;i++){
    int chunk = t + i*256;
    fv[i] = *(const f32x4*)(fbase + (chunk >> 4)*64 + (chunk & 15)*4);
  }
  // prefetch A-frags (global, independent)
  bf16x8 Am[2];
  #pragma unroll
  for (int kc=0;kc<2;kc++)
    Am[kc] = *(const bf16x8*)&Meffb[(size_t)b*4096 + (w*16 + m)*64 + kc*32 + quad*8];

  gnCoef(ssum_l, b, t, gammaP, betaP, l, s_gnA, s_gnB);
  if (t < 64) s_beff[t] = beff[b*64 + t];
  if (t < 16) s_sacc[t] = 0.f;
  __syncthreads();

  #pragma unroll
  for (int i=0;i<8;i++){
    int chunk = t + i*256;
    int px = chunk >> 4, c0 = (chunk & 15)*4;
    short4v xs;
    #pragma unroll
    for (int j=0;j<4;j++)
      xs[j] = f2bs(fmaf(fv[i][j], s_gnA[c0+j], s_gnB[c0+j]));
    *(short4v*)&s_xn[px*72 + c0] = xs;
  }
  __syncthreads();

  bf16x8 Bf[2][8];
  #pragma unroll
  for (int kc=0;kc<2;kc++)
    #pragma unroll
    for (int nt=0;nt<8;nt++)
      Bf[kc][nt] = *(const bf16x8*)&s_xn[(nt*16+m)*72 + kc*32 + quad*8];

  f32x4 acc[8];
  f32x4 z4 = {0.f,0.f,0.f,0.f};
  #pragma unroll
  for (int nt=0;nt<8;nt++) acc[nt]=z4;
  #pragma unroll
  for (int kc=0;kc<2;kc++)
    #pragma unroll
    for (int nt=0;nt<8;nt++)
      acc[nt] = __builtin_amdgcn_mfma_f32_16x16x32_bf16(Am[kc], Bf[kc][nt], acc[nt], 0,0,0);

  // ---- direct RMW: C rows are 4 contiguous channels in [px][c] ----
  int c0 = w*16 + quad*4;
  f32x4 bev = *(const f32x4*)&s_beff[c0];
  float gsv = 0.f, gqv = 0.f;
  #pragma unroll
  for (int nt=0;nt<8;nt++){
    int px = nt*16 + m;
    float* fp = (float*)(fbase + px*64 + c0);
    f32x4 old = *(const f32x4*)fp;
    f32x4 res;
    #pragma unroll
    for (int j=0;j<4;j++){
      float o = old[j] + acc[nt][j] + bev[j];
      res[j] = o;
      gsv += o; gqv += o*o;
    }
    *(f32x4*)fp = res;
  }
  // group g = 2w + (quad>>1): reduce over 32-lane halves (bits 0..4)
  #pragma unroll
  for (int off=1; off<32; off<<=1){
    gsv += __shfl_xor(gsv, off, 64);
    gqv += __shfl_xor(gqv, off, 64);
  }
  if ((lane & 31) == 0){
    int g = 2*w + (lane >> 5);
    atomicAdd(&s_sacc[g*2], gsv);
    atomicAdd(&s_sacc[g*2+1], gqv);
  }
  __syncthreads();
  if (t < 16) atomicAdd(&ssum_next[(b*16 + t)*32], s_sacc[t]);
}

// ---------- conv3x3 64->2 + residual; feat [px][c], weights [o][k][c] ----------
__global__ void k_conv_out(const float* __restrict__ feat, const float* __restrict__ wt,
                           const float* __restrict__ bias,
                           const float* __restrict__ xin, float* __restrict__ out){
  int b = blockIdx.y;
  int y = blockIdx.x;
  int xx = threadIdx.x;
  float acc0 = bias[0], acc1 = bias[1];
  #pragma unroll
  for (int dy=-1; dy<=1; dy++){
    int yy = y + dy;
    if (yy < 0 || yy >= HDIM) continue;
    #pragma unroll
    for (int dx=-1; dx<=1; dx++){
      int xc = xx + dx;
      if (xc >= 0 && xc < HDIM){
        const float* fp = feat + ((size_t)b*NPIX + yy*HDIM + xc)*64;
        const float* w0 = wt + ((0*3 + dy+1)*3 + dx+1)*64;
        const float* w1 = wt + ((1*3 + dy+1)*3 + dx+1)*64;
        #pragma unroll
        for (int c4=0;c4<16;c4++){
          f32x4 fvv = *(const f32x4*)(fp + c4*4);
          f32x4 wv0 = *(const f32x4*)(w0 + c4*4);
          f32x4 wv1 = *(const f32x4*)(w1 + c4*4);
          #pragma unroll
          for (int j=0;j<4;j++){
            acc0 += fvv[j]*wv0[j];
            acc1 += fvv[j]*wv1[j];
          }
        }
      }
    }
  }
  size_t p0 = (size_t)(b*2+0)*NPIX + y*HDIM + xx;
  size_t p1 = (size_t)(b*2+1)*NPIX + y*HDIM + xx;
  out[p0] = acc0 + xin[p0];
  out[p1] = acc1 + xin[p1];
}

extern "C" void kernel_launch(void* const* d_in, const int* in_sizes, int n_in,
                              void* d_out, int out_size, void* d_ws, size_t ws_size,
                              hipStream_t stream){
  char* ws = (char*)d_ws;
  float* feat  = (float*)(ws + OFS_FEAT);
  float* kxb   = (float*)(ws + OFS_KX);
  float* fsum  = (float*)(ws + OFS_FSUM);
  float* kgs   = (float*)(ws + OFS_KGS);
  float* ssum  = (float*)(ws + OFS_SSUM);
  float* beff  = (float*)(ws + OFS_BEFF);
  short* meffb = (short*)(ws + OFS_MEFFB);
  short* wkb   = (short*)(ws + OFS_WKB);
  short* wvb   = (short*)(ws + OFS_WVB);
  short* wgb   = (short*)(ws + OFS_WGB);
  float* wtout = (float*)(ws + OFS_WTOUT);
  short* wpb   = (short*)(ws + OFS_WPB);
  short* wqtb  = (short*)(ws + OFS_WQTB);

  const float* x      = (const float*)d_in[0];
  const float* hidden = (const float*)d_in[1];
  const float* W_in   = (const float*)d_in[2];
  const float* b_in   = (const float*)d_in[3];
  const float* gamma  = (const float*)d_in[4];
  const float* beta   = (const float*)d_in[5];
  const float* Wq     = (const float*)d_in[6];
  const float* bq     = (const float*)d_in[7];
  const float* Wk     = (const float*)d_in[8];
  const float* bk     = (const float*)d_in[9];
  const float* Wv     = (const float*)d_in[10];
  const float* bv     = (const float*)d_in[11];
  const float* Wg     = (const float*)d_in[12];
  const float* bg     = (const float*)d_in[13];
  const float* Wp     = (const float*)d_in[14];
  const float* bp     = (const float*)d_in[15];
  const float* W_out  = (const float*)d_in[16];
  const float* b_out  = (const float*)d_in[17];

  float* out        = (float*)d_out;
  float* hidden_out = out + BATCH*2*NPIX;

  hipMemsetAsync(ws + OFS_KX, 0, ZERO_BYTES, stream);
  k_prepw<<<dim3(128), dim3(256), 0, stream>>>(Wk, Wv, Wg, W_out, Wp, Wq,
                                               wkb, wvb, wgb, wtout, wpb, wqtb);
  k_conv_in<<<dim3(HDIM, BATCH), dim3(256), 0, stream>>>(x, W_in, b_in, feat, ssum);

  for (int l=0; l<NLAYER; l++){
    float* ssum_l = ssum + (l & 1)*1024;
    float* ssum_n = ssum + ((l+1) & 1)*1024;
    k_qkvg_know<<<dim3(NPIX/128, BATCH), dim3(256), 0, stream>>>(
        feat, ssum_l, gamma, beta, wkb, bk, wgb, bg, l, kxb, fsum, kgs);
    k_memupd_meff<<<dim3(BATCH), dim3(256), 0, stream>>>(
        kxb, fsum, kgs, hidden, wvb, bv, wpb, wqtb, bq, bp, l, hidden_out,
        meffb, beff, ssum_n);
    k_retrproj<<<dim3(NPIX/128, BATCH), dim3(256), 0, stream>>>(
        ssum_l, gamma, beta, meffb, beff, l, feat, ssum_n);
  }

  k_conv_out<<<dim3(HDIM, BATCH), dim3(256), 0, stream>>>(feat, wtout, b_out, x, out);
}